// Round 2
// baseline (259.336 us; speedup 1.0000x reference)
//
#include <hip/hip_runtime.h>

// AMPS chain kernel v2 — segmented-parallel, MI355X/gfx950.
//
// The serial 1x4 @ 4x4 chain per (n, batch) is associative: split chain n
// (n+1 steps) into 128-step segments. Kernel 1 (amps_seg) computes each
// segment's full 4x4 matrix product in parallel (one 128-thread block per
// (chain, segment); lanes = 8 batches x 4 rows x 4 cols; DPP quad_perm
// broadcast for the k-dot). Kernel 2 (amps_combine) multiplies the <=8
// segment matrices per (chain, batch) in order, applies diag + log-softmax
// + data-bit selection, writes per-position partials. Kernel 3 reduces.
//
// ws layout: [0, 4190208): segment products (1023 x 8 x 8 x 16 floats)
//            [4190208, +32KB): partials (1024 x 8 floats)

#define NPOS   1024
#define BATCH  8
#define SEGLEN 128
#define MAXSEG 8
#define UNROLL 8

template<int l>
__device__ __forceinline__ float qb(float x) {
    // quad_perm broadcast lane l within each group of 4 lanes
    constexpr int ctrl = l * 0x55;
    return __int_as_float(__builtin_amdgcn_update_dpp(
        __float_as_int(x), __float_as_int(x), ctrl, 0xF, 0xF, false));
}

template<int ctrl>
__device__ __forceinline__ float qperm(float x) {
    return __int_as_float(__builtin_amdgcn_update_dpp(
        __float_as_int(x), __float_as_int(x), ctrl, 0xF, 0xF, false));
}

__global__ __launch_bounds__(128) void amps_seg(
        const float* __restrict__ data,   // (8, 1024)
        const float* __restrict__ tri,    // (523776, 4, 4, 2)
        float* __restrict__ segout)       // (1023, 8, 8, 16)
{
    const int n  = blockIdx.x;            // chain 0..1022
    const int s  = blockIdx.y;            // segment 0..7
    const int g0 = s * SEGLEN;
    if (g0 > n) return;
    const int steps = min(SEGLEN, n + 1 - g0);

    const int tid = threadIdx.x;
    const int b = tid >> 4;               // batch 0..7
    const int i = (tid >> 2) & 3;         // row of C
    const int j = tid & 3;                // col of C

    const float* __restrict__ tp = tri + ((size_t)n * (n + 1) / 2 + g0) * 32;
    const float* __restrict__ dp = data + b * NPOS + g0;

    float c = (i == j) ? 1.0f : 0.0f;     // C starts as identity

    float tA[UNROLL * 4], tB[UNROLL * 4];
    float dA[UNROLL],     dB[UNROLL];

    auto dload = [&](float (&dst)[UNROLL], int k) {
        const float4* p = (const float4*)(dp + k * UNROLL);
        #pragma unroll
        for (int q = 0; q < UNROLL / 4; q++) {
            float4 t = p[q];
            dst[q*4+0] = t.x; dst[q*4+1] = t.y; dst[q*4+2] = t.z; dst[q*4+3] = t.w;
        }
    };
    auto tload = [&](float (&tb)[UNROLL * 4], const float (&db)[UNROLL], int k) {
        const float* bp = tp + (size_t)k * UNROLL * 32 + j * 2;
        #pragma unroll
        for (int m = 0; m < UNROLL; m++) {
            // M[k][j] at element k*8 + j*2 + sel within the step's 32-float block
            const float* q = bp + m * 32 + ((db[m] == 1.0f) ? 0 : 1);
            tb[m*4+0] = q[0];  tb[m*4+1] = q[8];
            tb[m*4+2] = q[16]; tb[m*4+3] = q[24];
        }
    };
    auto comp = [&](const float (&tb)[UNROLL * 4]) {
        #pragma unroll
        for (int m = 0; m < UNROLL; m++) {
            // C[i][j] = sum_k C[i][k] * M[k][j]; qb<k> broadcasts C[i][k] in quad
            float acc = qb<0>(c) * tb[m*4+0];
            acc = fmaf(qb<1>(c), tb[m*4+1], acc);
            acc = fmaf(qb<2>(c), tb[m*4+2], acc);
            c   = fmaf(qb<3>(c), tb[m*4+3], acc);
        }
    };

    const int nfull = steps / UNROLL;
    if (nfull > 0) {
        const int last = nfull - 1;
        dload(dA, 0);
        dload(dB, (1 < last) ? 1 : last);
        tload(tA, dA, 0);
        for (int k = 0; k < nfull; k += 2) {
            dload(dA, (k + 2 < last) ? k + 2 : last);
            const bool has1 = (k + 1 < nfull);
            if (has1) tload(tB, dB, k + 1);
            comp(tA);
            if (has1) {
                dload(dB, (k + 3 < last) ? k + 3 : last);
                if (k + 2 < nfull) tload(tA, dA, k + 2);
                comp(tB);
            }
        }
    }
    for (int m = nfull * UNROLL; m < steps; m++) {
        float d = dp[m];
        const float* q = tp + (size_t)m * 32 + j * 2 + ((d == 1.0f) ? 0 : 1);
        float acc = qb<0>(c) * q[0];
        acc = fmaf(qb<1>(c), q[8],  acc);
        acc = fmaf(qb<2>(c), q[16], acc);
        c   = fmaf(qb<3>(c), q[24], acc);
    }

    segout[(((size_t)n * MAXSEG + s) * BATCH + b) * 16 + i * 4 + j] = c;
}

__global__ __launch_bounds__(64) void amps_combine(
        const float* __restrict__ segout, // (1023, 8, 8, 16)
        const float* __restrict__ diag,   // (1024, 4, 2)
        const float* __restrict__ data,   // (8, 1024)
        float* __restrict__ partials)     // (1024, 8)
{
    const int n    = blockIdx.x;          // chain 0..1022
    const int lane = threadIdx.x;
    const int b    = (lane >> 2) & 7;
    const int r    = lane & 3;

    const int nseg = n / SEGLEN + 1;      // ceil((n+1)/128)
    float v = (r == 0) ? 1.0f : 0.0f;     // e0 row

    for (int s = 0; s < nseg; s++) {
        // v_new[j] = sum_k v[k] * P[k][j]; lane r=j reads P[k][r] = seg[k*4+r]
        const float* p = segout + (((size_t)n * MAXSEG + s) * BATCH + b) * 16 + r;
        float p0 = p[0], p1 = p[4], p2 = p[8], p3 = p[12];
        float acc = qb<0>(v) * p0;
        acc = fmaf(qb<1>(v), p1, acc);
        acc = fmaf(qb<2>(v), p2, acc);
        v   = fmaf(qb<3>(v), p3, acc);
    }

    const int pos = n + 1;
    const float* dg = diag + pos * 8 + r * 2;
    float o0 = v * dg[0];
    float o1 = v * dg[1];
    o0 += qperm<0xB1>(o0); o0 += qperm<0x4E>(o0);   // quad sum over r
    o1 += qperm<0xB1>(o1); o1 += qperm<0x4E>(o1);
    float mx  = fmaxf(o0, o1);
    float lse = mx + __logf(__expf(o0 - mx) + __expf(o1 - mx));
    float dsel = data[b * NPOS + pos];
    if (lane < 32 && r == 0)
        partials[pos * BATCH + b] = ((dsel == 1.0f) ? o0 : o1) - lse;
}

__global__ __launch_bounds__(64) void amps_reduce(
        const float* __restrict__ partials,
        const float* __restrict__ diag,
        const float* __restrict__ data,
        float* __restrict__ out)
{
    const int t = threadIdx.x;            // 64 threads
    const int b = t & 7, g = t >> 3;
    float s = 0.0f;
    for (int k = g; k < NPOS; k += 8)
        if (k > 0) s += partials[k * BATCH + b];
    if (g == 0) {
        // position-0 term: logits = diag[0,0,:]
        float o0 = diag[0], o1 = diag[1];
        float mx  = fmaxf(o0, o1);
        float lse = mx + __logf(__expf(o0 - mx) + __expf(o1 - mx));
        float d0  = data[b * NPOS];
        s += ((d0 == 1.0f) ? o0 : o1) - lse;
    }
    s += __shfl_down(s, 32);
    s += __shfl_down(s, 16);
    s += __shfl_down(s, 8);
    if (t < 8) out[t] = s;
}

extern "C" void kernel_launch(void* const* d_in, const int* in_sizes, int n_in,
                              void* d_out, int out_size, void* d_ws, size_t ws_size,
                              hipStream_t stream)
{
    const float* data = (const float*)d_in[0];   // (8, 1024)
    const float* tri  = (const float*)d_in[1];   // (523776, 4, 4, 2)
    const float* diag = (const float*)d_in[2];   // (1024, 4, 2)

    float* segout   = (float*)d_ws;                       // 4,190,208 B
    float* partials = (float*)((char*)d_ws + (size_t)1023 * MAXSEG * BATCH * 16 * 4);
    float* out = (float*)d_out;                           // 8 floats

    amps_seg<<<dim3(NPOS - 1, MAXSEG), dim3(128), 0, stream>>>(data, tri, segout);
    amps_combine<<<dim3(NPOS - 1), dim3(64), 0, stream>>>(segout, diag, data, partials);
    amps_reduce<<<dim3(1), dim3(64), 0, stream>>>(partials, diag, data, out);
}

// Round 3
// 128.061 us; speedup vs baseline: 2.0251x; 2.0251x over previous
//
#include <hip/hip_runtime.h>

// AMPS chain kernel v3 — segmented + LDS-staged, MI355X/gfx950.
//
// amps_seg: one wave per (chain n, 128-step segment). Lane = (b, i2, j):
// batch b=lane>>3, row-pair i2=(lane>>2)&1 (rows i2, i2+2), col j=lane&3.
// Each lane carries C[i2][j] and C[i2+2][j]; quad_perm DPP broadcasts C[.][k]
// for the 4-term dot (2 independent FMA chains -> ILP 2).
// tri staged to LDS via global_load_lds width=16: 2 VMEM instr / 16-step chunk
// (vs 64 scalar gathers before). Triple-buffered (3 x 2KB), constant-distance
// pipeline with manual s_waitcnt vmcnt(6) -> 2 chunks always in flight.
// Per-step gather = 2 x ds_read2_b32 from LDS (8 banks, broadcast; no conflict).
//
// amps_combine: 8 chains/block (256 thr), multiplies <=8 segment matrices,
// diag + log-softmax + data-bit select, block LDS reduce, 8 atomicAdds.

#define NPOS   1024
#define BATCH  8
#define SEGLEN 128
#define MAXSEG 8
#define CH     16
#define TRI_ELEMS (523776 * 32)       // total floats in tri

template<int l>
__device__ __forceinline__ float qb(float x) {
    constexpr int ctrl = l * 0x55;    // quad_perm broadcast lane l
    return __int_as_float(__builtin_amdgcn_update_dpp(
        __float_as_int(x), __float_as_int(x), ctrl, 0xF, 0xF, false));
}
template<int ctrl>
__device__ __forceinline__ float qperm(float x) {
    return __int_as_float(__builtin_amdgcn_update_dpp(
        __float_as_int(x), __float_as_int(x), ctrl, 0xF, 0xF, false));
}

__device__ __forceinline__ void gl_lds16(const float* g, float* l) {
    // per-lane global addr; LDS dst = uniform base + lane*16
    __builtin_amdgcn_global_load_lds(
        (const __attribute__((address_space(1))) void*)g,
        (__attribute__((address_space(3))) void*)l, 16, 0, 0);
}

// wait until <=N vmem ops outstanding; ignore lgkm/exp (gfx9 encoding)
#define WAITVM(N) __builtin_amdgcn_s_waitcnt((N) | 0x0F70)

__global__ __launch_bounds__(64) void amps_seg(
        const float* __restrict__ data,   // (8, 1024)
        const float* __restrict__ tri,    // (523776, 4, 4, 2)
        float* __restrict__ segout)       // (1023, 8, 8, 16)
{
    const int n  = blockIdx.x;            // chain 0..1022
    const int s  = blockIdx.y;            // segment 0..7
    const int g0 = s * SEGLEN;
    if (g0 > n) return;
    const int steps = min(SEGLEN, n + 1 - g0);

    const int tid = threadIdx.x;
    const int b   = tid >> 3;             // batch
    const int i2  = (tid >> 2) & 1;       // row pair: rows i2, i2+2
    const int j   = tid & 3;              // col

    __shared__ float lds[3 * CH * 32];    // 3 x 512 floats (2KB each)

    const int tstart = (n * (n + 1) / 2 + g0) * 32;   // float index, < 2^25
    const float* __restrict__ dp = data + b * NPOS + g0;

    const int full = steps >> 4;
    const int rem  = steps & 15;

    // stage 16 steps (2KB) of tri into LDS buffer at float-offset bufoff
    auto stage = [&](int cc, int bufoff) {
        int o0 = min(tstart + cc * 512 + tid * 4,       TRI_ELEMS - 4);
        int o1 = min(tstart + cc * 512 + 256 + tid * 4, TRI_ELEMS - 4);
        gl_lds16(tri + o0, (float*)lds + bufoff);
        gl_lds16(tri + o1, (float*)lds + bufoff + 256);
    };
    // load 16 data bits for chunk cc (row-clamped; redundant per b-octet, L1-hit)
    auto dload = [&](int cc, float4* d) {
        int o = min(cc * CH, (NPOS - CH) - g0);
        const float4* p = (const float4*)(dp + o);
        d[0] = p[0]; d[1] = p[1]; d[2] = p[2]; d[3] = p[3];
    };

    float c_lo = (i2     == j) ? 1.0f : 0.0f;
    float c_hi = (i2 + 2 == j) ? 1.0f : 0.0f;

    auto compute = [&](int bufoff, const float4* d, int msteps) {
        float dv[16] = { d[0].x,d[0].y,d[0].z,d[0].w, d[1].x,d[1].y,d[1].z,d[1].w,
                         d[2].x,d[2].y,d[2].z,d[2].w, d[3].x,d[3].y,d[3].z,d[3].w };
        #pragma unroll
        for (int m = 0; m < CH; m++) {
            if (m >= msteps) break;       // uniform; folds away when msteps==16
            int base = bufoff + m * 32 + j * 2 + ((dv[m] == 1.0f) ? 0 : 1);
            float t0 = lds[base],      t1 = lds[base + 8];
            float t2 = lds[base + 16], t3 = lds[base + 24];
            float nl = qb<0>(c_lo) * t0;
            nl = fmaf(qb<1>(c_lo), t1, nl);
            nl = fmaf(qb<2>(c_lo), t2, nl);
            nl = fmaf(qb<3>(c_lo), t3, nl);
            float nh = qb<0>(c_hi) * t0;
            nh = fmaf(qb<1>(c_hi), t1, nh);
            nh = fmaf(qb<2>(c_hi), t2, nh);
            nh = fmaf(qb<3>(c_hi), t3, nh);
            c_lo = nl; c_hi = nh;
        }
    };

    float4 dA[4], dB[4];
    // prologue: chunks 0,1 staged; data chunk 0 (8 vmem ops total)
    stage(0, 0);
    stage(1, 512);
    dload(0, dA);

    int bc = 0, bn = 512, bn2 = 1024;     // LDS bufs for chunks c, c+1, c+2
    int c = 0;
    // steady state: each iter issues stage(c+2)=2 + dload(c+1)=4 ops, then
    // vmcnt(6) leaves exactly those 6 in flight => stage(c)/data(c) complete.
    while (c + 1 < full) {
        stage(c + 2, bn2); dload(c + 1, dB);
        WAITVM(6);
        compute(bc, dA, CH);
        { int t = bc; bc = bn; bn = bn2; bn2 = t; } c++;
        stage(c + 2, bn2); dload(c + 1, dA);
        WAITVM(6);
        compute(bc, dB, CH);
        { int t = bc; bc = bn; bn = bn2; bn2 = t; } c++;
    }
    if (c < full) {                        // odd count of full chunks
        stage(c + 2, bn2); dload(c + 1, dB);
        WAITVM(6);
        compute(bc, dA, CH);
        { int t = bc; bc = bn; bn = bn2; bn2 = t; } c++;
    }
    if (rem) {                             // tail chunk index = full
        WAITVM(0);
        if (full & 1) compute(bc, dB, rem);
        else          compute(bc, dA, rem);
    }

    const size_t o = (((size_t)n * MAXSEG + s) * BATCH + b) * 16;
    segout[o + i2 * 4 + j]       = c_lo;
    segout[o + (i2 + 2) * 4 + j] = c_hi;
}

__global__ __launch_bounds__(256) void amps_combine(
        const float* __restrict__ segout, // (1023, 8, 8, 16)
        const float* __restrict__ diag,   // (1024, 4, 2)
        const float* __restrict__ data,   // (8, 1024)
        float* __restrict__ out)          // (8) — must be pre-zeroed
{
    const int tid = threadIdx.x;
    const int q   = tid >> 5;             // chain slot in block, 0..7
    const int sub = tid & 31;
    const int b   = sub >> 2;
    const int r   = sub & 3;
    const int n   = blockIdx.x * 8 + q;   // 0..1023 (1023 invalid)

    __shared__ float sh[64];

    float res = 0.0f;
    if (n < NPOS - 1) {
        const int nseg = n / SEGLEN + 1;
        float v = (r == 0) ? 1.0f : 0.0f;
        for (int s2 = 0; s2 < nseg; s2++) {
            const float* p = segout + (((size_t)n * MAXSEG + s2) * BATCH + b) * 16 + r;
            float p0 = p[0], p1 = p[4], p2 = p[8], p3 = p[12];
            float acc = qb<0>(v) * p0;
            acc = fmaf(qb<1>(v), p1, acc);
            acc = fmaf(qb<2>(v), p2, acc);
            v   = fmaf(qb<3>(v), p3, acc);
        }
        const int pos = n + 1;
        const float* dg = diag + pos * 8 + r * 2;
        float o0 = v * dg[0];
        float o1 = v * dg[1];
        o0 += qperm<0xB1>(o0); o0 += qperm<0x4E>(o0);   // quad sum over r
        o1 += qperm<0xB1>(o1); o1 += qperm<0x4E>(o1);
        float mx  = fmaxf(o0, o1);
        float lse = mx + __logf(__expf(o0 - mx) + __expf(o1 - mx));
        float dsel = data[b * NPOS + pos];
        res = ((dsel == 1.0f) ? o0 : o1) - lse;
    }
    if (r == 0) sh[q * 8 + b] = res;
    __syncthreads();
    if (tid < 8) {                        // one lane per batch
        float ssum = 0.0f;
        #pragma unroll
        for (int qq = 0; qq < 8; qq++) ssum += sh[qq * 8 + tid];
        if (blockIdx.x == 0) {
            // position-0 term: logits = diag[0,0,:]
            float o0 = diag[0], o1 = diag[1];
            float mx  = fmaxf(o0, o1);
            float lse = mx + __logf(__expf(o0 - mx) + __expf(o1 - mx));
            float d0  = data[tid * NPOS];
            ssum += ((d0 == 1.0f) ? o0 : o1) - lse;
        }
        atomicAdd(out + tid, ssum);
    }
}

extern "C" void kernel_launch(void* const* d_in, const int* in_sizes, int n_in,
                              void* d_out, int out_size, void* d_ws, size_t ws_size,
                              hipStream_t stream)
{
    const float* data = (const float*)d_in[0];   // (8, 1024)
    const float* tri  = (const float*)d_in[1];   // (523776, 4, 4, 2)
    const float* diag = (const float*)d_in[2];   // (1024, 4, 2)

    float* segout = (float*)d_ws;                // 1023*8*8*16*4 = 4,190,208 B
    float* out    = (float*)d_out;               // 8 floats

    hipMemsetAsync(d_out, 0, 8 * sizeof(float), stream);
    amps_seg<<<dim3(NPOS - 1, MAXSEG), dim3(64), 0, stream>>>(data, tri, segout);
    amps_combine<<<dim3(128), dim3(256), 0, stream>>>(segout, diag, data, out);
}

// Round 4
// 120.981 us; speedup vs baseline: 2.1436x; 1.0585x over previous
//
#include <hip/hip_runtime.h>

// AMPS chain kernel v4 — segmented + LDS-staged + occupancy-fixed. gfx950.
//
// v3 -> v4: amps_seg now uses a FLAT task list (4600 real (chain,segment)
// tasks, no dead blocks) with 4 independent waves per 256-thread block
// sharing one 24KB LDS allocation -> 6 blocks/CU = 24 waves/CU, and the
// whole grid (1150 blocks) is co-resident (capacity 1536) -> no dispatch
// tail. Inner loop identical to v3: tri staged to LDS via
// global_load_lds width=16 (2 VMEM/16-step chunk), triple-buffered with
// manual s_waitcnt vmcnt(6); per-step 2x ds_read2_b32 + quad_perm DPP
// broadcast FMA chain (2 C-rows per lane).

#define NPOS   1024
#define BATCH  8
#define SEGLEN 128
#define MAXSEG 8
#define CH     16
#define NTASK  4600                    // sum_{s=0}^{7} (1023 - 128 s)
#define TRI_ELEMS (523776 * 32)        // total floats in tri

template<int l>
__device__ __forceinline__ float qb(float x) {
    constexpr int ctrl = l * 0x55;     // quad_perm broadcast lane l
    return __int_as_float(__builtin_amdgcn_update_dpp(
        __float_as_int(x), __float_as_int(x), ctrl, 0xF, 0xF, false));
}
template<int ctrl>
__device__ __forceinline__ float qperm(float x) {
    return __int_as_float(__builtin_amdgcn_update_dpp(
        __float_as_int(x), __float_as_int(x), ctrl, 0xF, 0xF, false));
}

__device__ __forceinline__ void gl_lds16(const float* g, float* l) {
    __builtin_amdgcn_global_load_lds(
        (const __attribute__((address_space(1))) void*)g,
        (__attribute__((address_space(3))) void*)l, 16, 0, 0);
}

// wait until <=N vmem ops outstanding; ignore lgkm/exp (gfx9 encoding)
#define WAITVM(N) __builtin_amdgcn_s_waitcnt((N) | 0x0F70)

__global__ __launch_bounds__(256, 6) void amps_seg(
        const float* __restrict__ data,   // (8, 1024)
        const float* __restrict__ tri,    // (523776, 4, 4, 2)
        float* __restrict__ segout)       // (1023, 8, 8, 16)
{
    const int tid  = threadIdx.x;
    const int wid  = tid >> 6;
    const int lane = tid & 63;
    const int id   = blockIdx.x * 4 + wid;        // task 0..4599

    // task -> (segment s, chain n); long tasks (big n) first within each s
    int s = 0, base = 0, cnt = 1023;
    while (id >= base + cnt) { base += cnt; s++; cnt -= 128; }
    const int n  = 1022 - (id - base);
    const int g0 = s * SEGLEN;
    const int steps = min(SEGLEN, n + 1 - g0);

    const int b  = lane >> 3;             // batch
    const int i2 = (lane >> 2) & 1;       // row pair: rows i2, i2+2
    const int j  = lane & 3;              // col

    __shared__ float lds_all[4][3 * CH * 32];     // 4 waves x 3 x 2KB
    float* __restrict__ lds = &lds_all[wid][0];

    const int tstart = (n * (n + 1) / 2 + g0) * 32;
    const float* __restrict__ dp = data + b * NPOS + g0;

    const int full = steps >> 4;
    const int rem  = steps & 15;

    auto stage = [&](int cc, int bufoff) {
        int o0 = min(tstart + cc * 512 + lane * 4,       TRI_ELEMS - 4);
        int o1 = min(tstart + cc * 512 + 256 + lane * 4, TRI_ELEMS - 4);
        gl_lds16(tri + o0, lds + bufoff);
        gl_lds16(tri + o1, lds + bufoff + 256);
    };
    auto dload = [&](int cc, float4* d) {
        int o = min(cc * CH, (NPOS - CH) - g0);
        const float4* p = (const float4*)(dp + o);
        d[0] = p[0]; d[1] = p[1]; d[2] = p[2]; d[3] = p[3];
    };

    float c_lo = (i2     == j) ? 1.0f : 0.0f;
    float c_hi = (i2 + 2 == j) ? 1.0f : 0.0f;

    auto compute = [&](int bufoff, const float4* d, int msteps) {
        float dv[16] = { d[0].x,d[0].y,d[0].z,d[0].w, d[1].x,d[1].y,d[1].z,d[1].w,
                         d[2].x,d[2].y,d[2].z,d[2].w, d[3].x,d[3].y,d[3].z,d[3].w };
        #pragma unroll
        for (int m = 0; m < CH; m++) {
            if (m >= msteps) break;       // wave-uniform; folds when msteps==16
            int bi = bufoff + m * 32 + j * 2 + ((dv[m] == 1.0f) ? 0 : 1);
            float t0 = lds[bi],      t1 = lds[bi + 8];
            float t2 = lds[bi + 16], t3 = lds[bi + 24];
            float nl = qb<0>(c_lo) * t0;
            nl = fmaf(qb<1>(c_lo), t1, nl);
            nl = fmaf(qb<2>(c_lo), t2, nl);
            nl = fmaf(qb<3>(c_lo), t3, nl);
            float nh = qb<0>(c_hi) * t0;
            nh = fmaf(qb<1>(c_hi), t1, nh);
            nh = fmaf(qb<2>(c_hi), t2, nh);
            nh = fmaf(qb<3>(c_hi), t3, nh);
            c_lo = nl; c_hi = nh;
        }
    };

    float4 dA[4], dB[4];
    stage(0, 0);
    stage(1, 512);
    dload(0, dA);

    int bc = 0, bn = 512, bn2 = 1024;
    int c = 0;
    while (c + 1 < full) {
        stage(c + 2, bn2); dload(c + 1, dB);
        WAITVM(6);
        compute(bc, dA, CH);
        { int t = bc; bc = bn; bn = bn2; bn2 = t; } c++;
        stage(c + 2, bn2); dload(c + 1, dA);
        WAITVM(6);
        compute(bc, dB, CH);
        { int t = bc; bc = bn; bn = bn2; bn2 = t; } c++;
    }
    if (c < full) {
        stage(c + 2, bn2); dload(c + 1, dB);
        WAITVM(6);
        compute(bc, dA, CH);
        { int t = bc; bc = bn; bn = bn2; bn2 = t; } c++;
    }
    if (rem) {
        WAITVM(0);
        if (full & 1) compute(bc, dB, rem);
        else          compute(bc, dA, rem);
    }

    const size_t o = (((size_t)n * MAXSEG + s) * BATCH + b) * 16;
    segout[o + i2 * 4 + j]       = c_lo;
    segout[o + (i2 + 2) * 4 + j] = c_hi;
}

__global__ __launch_bounds__(256) void amps_combine(
        const float* __restrict__ segout, // (1023, 8, 8, 16)
        const float* __restrict__ diag,   // (1024, 4, 2)
        const float* __restrict__ data,   // (8, 1024)
        float* __restrict__ out)          // (8) — pre-zeroed by memset
{
    const int tid = threadIdx.x;
    const int q   = tid >> 5;             // chain slot in block, 0..7
    const int sub = tid & 31;
    const int b   = sub >> 2;
    const int r   = sub & 3;
    const int n   = blockIdx.x * 8 + q;   // 0..1023 (1023 invalid)

    __shared__ float sh[64];

    float res = 0.0f;
    if (n < NPOS - 1) {
        const int nseg = n / SEGLEN + 1;
        float v = (r == 0) ? 1.0f : 0.0f;
        for (int s2 = 0; s2 < nseg; s2++) {
            const float* p = segout + (((size_t)n * MAXSEG + s2) * BATCH + b) * 16 + r;
            float p0 = p[0], p1 = p[4], p2 = p[8], p3 = p[12];
            float acc = qb<0>(v) * p0;
            acc = fmaf(qb<1>(v), p1, acc);
            acc = fmaf(qb<2>(v), p2, acc);
            v   = fmaf(qb<3>(v), p3, acc);
        }
        const int pos = n + 1;
        const float* dg = diag + pos * 8 + r * 2;
        float o0 = v * dg[0];
        float o1 = v * dg[1];
        o0 += qperm<0xB1>(o0); o0 += qperm<0x4E>(o0);   // quad sum over r
        o1 += qperm<0xB1>(o1); o1 += qperm<0x4E>(o1);
        float mx  = fmaxf(o0, o1);
        float lse = mx + __logf(__expf(o0 - mx) + __expf(o1 - mx));
        float dsel = data[b * NPOS + pos];
        res = ((dsel == 1.0f) ? o0 : o1) - lse;
    }
    if (r == 0) sh[q * 8 + b] = res;
    __syncthreads();
    if (tid < 8) {
        float ssum = 0.0f;
        #pragma unroll
        for (int qq = 0; qq < 8; qq++) ssum += sh[qq * 8 + tid];
        if (blockIdx.x == 0) {
            float o0 = diag[0], o1 = diag[1];
            float mx  = fmaxf(o0, o1);
            float lse = mx + __logf(__expf(o0 - mx) + __expf(o1 - mx));
            float d0  = data[tid * NPOS];
            ssum += ((d0 == 1.0f) ? o0 : o1) - lse;
        }
        atomicAdd(out + tid, ssum);
    }
}

extern "C" void kernel_launch(void* const* d_in, const int* in_sizes, int n_in,
                              void* d_out, int out_size, void* d_ws, size_t ws_size,
                              hipStream_t stream)
{
    const float* data = (const float*)d_in[0];   // (8, 1024)
    const float* tri  = (const float*)d_in[1];   // (523776, 4, 4, 2)
    const float* diag = (const float*)d_in[2];   // (1024, 4, 2)

    float* segout = (float*)d_ws;                // 1023*8*8*16*4 = 4,190,208 B
    float* out    = (float*)d_out;               // 8 floats

    hipMemsetAsync(d_out, 0, 8 * sizeof(float), stream);
    amps_seg<<<dim3(NTASK / 4), dim3(256), 0, stream>>>(data, tri, segout);
    amps_combine<<<dim3(128), dim3(256), 0, stream>>>(segout, diag, data, out);
}

// Round 5
// 120.672 us; speedup vs baseline: 2.1491x; 1.0026x over previous
//
#include <hip/hip_runtime.h>

// AMPS chain kernel v5 — clean-queue pipeline. gfx950.
//
// v4 -> v5: data bit loads are hoisted out of the K-loop. At segment start
// each lane loads 16 data floats (the wave cooperatively covers all 8
// batches x 128 positions), packs a 16-bit "sel" piece, and assembles its
// batch's full 128-bit mask via __shfl from its batch-octet. The K-loop's
// VMEM queue then holds ONLY global_load_lds ops, so WAITVM(4) gives a true
// 2-chunk (~1400 cyc) prefetch distance with no register-dependency drag
// (vmcnt completion is in-order; v4's interleaved data loads forced the
// next tri stage to drain every iteration -> latency exposure).
// Inner math unchanged: 2x ds_read2_b32 + quad_perm DPP broadcast FMA,
// two C-rows per lane. Flat task list, 4 waves/block, 3x2KB LDS per wave.

#define NPOS   1024
#define BATCH  8
#define SEGLEN 128
#define MAXSEG 8
#define CH     16
#define NTASK  4600                    // sum_{s=0}^{7} (1023 - 128 s)
#define TRI_ELEMS (523776 * 32)        // total floats in tri

template<int l>
__device__ __forceinline__ float qb(float x) {
    constexpr int ctrl = l * 0x55;     // quad_perm broadcast lane l
    return __int_as_float(__builtin_amdgcn_update_dpp(
        __float_as_int(x), __float_as_int(x), ctrl, 0xF, 0xF, false));
}
template<int ctrl>
__device__ __forceinline__ float qperm(float x) {
    return __int_as_float(__builtin_amdgcn_update_dpp(
        __float_as_int(x), __float_as_int(x), ctrl, 0xF, 0xF, false));
}

__device__ __forceinline__ void gl_lds16(const float* g, float* l) {
    __builtin_amdgcn_global_load_lds(
        (const __attribute__((address_space(1))) void*)g,
        (__attribute__((address_space(3))) void*)l, 16, 0, 0);
}

// wait until <=N vmem ops outstanding; ignore lgkm/exp (gfx9 encoding)
#define WAITVM(N) __builtin_amdgcn_s_waitcnt((N) | 0x0F70)

__global__ __launch_bounds__(256, 6) void amps_seg(
        const float* __restrict__ data,   // (8, 1024)
        const float* __restrict__ tri,    // (523776, 4, 4, 2)
        float* __restrict__ segout)       // (1023, 8, 8, 16)
{
    const int tid  = threadIdx.x;
    const int wid  = tid >> 6;
    const int lane = tid & 63;
    const int id   = blockIdx.x * 4 + wid;        // task 0..4599

    // task -> (segment s, chain n); long tasks (big n) first within each s
    int s = 0, base = 0, cnt = 1023;
    while (id >= base + cnt) { base += cnt; s++; cnt -= 128; }
    const int n  = 1022 - (id - base);
    const int g0 = s * SEGLEN;
    const int steps = min(SEGLEN, n + 1 - g0);

    const int b   = lane >> 3;            // batch
    const int sub = lane & 7;             // i2*4 + j
    const int i2  = (lane >> 2) & 1;      // row pair: rows i2, i2+2
    const int j   = lane & 3;             // col

    __shared__ float lds_all[4][3 * CH * 32];     // 4 waves x 3 x 2KB
    float* __restrict__ lds = &lds_all[wid][0];

    const int tstart = (n * (n + 1) / 2 + g0) * 32;
    const int full = steps >> 4;
    const int rem  = steps & 15;

    auto stage = [&](int cc, int bufoff) {
        int o0 = min(tstart + cc * 512 + lane * 4,       TRI_ELEMS - 4);
        int o1 = min(tstart + cc * 512 + 256 + lane * 4, TRI_ELEMS - 4);
        gl_lds16(tri + o0, lds + bufoff);
        gl_lds16(tri + o1, lds + bufoff + 256);
    };

    // kick off first two tri stages before building the mask
    stage(0, 0);
    stage(1, 512);

    // --- build per-lane 128-bit sel mask (sel=1 where data != 1.0) ---
    // lane covers positions [sub*16, sub*16+16) of its own batch row;
    // the batch-octet's 8 lanes cover all 128 positions.
    unsigned mask[4];
    {
        const float4* dp4 = (const float4*)(data + b * NPOS + g0 + sub * 16);
        float4 q0 = dp4[0], q1 = dp4[1], q2 = dp4[2], q3 = dp4[3];
        float dv[16] = { q0.x,q0.y,q0.z,q0.w, q1.x,q1.y,q1.z,q1.w,
                         q2.x,q2.y,q2.z,q2.w, q3.x,q3.y,q3.z,q3.w };
        unsigned piece = 0;
        #pragma unroll
        for (int t = 0; t < 16; t++)
            piece |= (dv[t] != 1.0f) ? (1u << t) : 0u;
        #pragma unroll
        for (int w = 0; w < 4; w++) {
            unsigned lo = (unsigned)__shfl((int)piece, b * 8 + 2 * w);
            unsigned hi = (unsigned)__shfl((int)piece, b * 8 + 2 * w + 1);
            mask[w] = lo | (hi << 16);
        }
    }

    float c_lo = (i2     == j) ? 1.0f : 0.0f;
    float c_hi = (i2 + 2 == j) ? 1.0f : 0.0f;

    auto compute = [&](int bufoff, unsigned bits, int msteps) {
        const int bj = bufoff + j * 2;
        #pragma unroll
        for (int m = 0; m < CH; m++) {
            if (m >= msteps) break;       // wave-uniform; folds when msteps==16
            int bi = bj + m * 32 + ((bits >> m) & 1u);
            float t0 = lds[bi],      t1 = lds[bi + 8];
            float t2 = lds[bi + 16], t3 = lds[bi + 24];
            float nl = qb<0>(c_lo) * t0;
            nl = fmaf(qb<1>(c_lo), t1, nl);
            nl = fmaf(qb<2>(c_lo), t2, nl);
            nl = fmaf(qb<3>(c_lo), t3, nl);
            float nh = qb<0>(c_hi) * t0;
            nh = fmaf(qb<1>(c_hi), t1, nh);
            nh = fmaf(qb<2>(c_hi), t2, nh);
            nh = fmaf(qb<3>(c_hi), t3, nh);
            c_lo = nl; c_hi = nh;
        }
    };

    auto bits_of = [&](int cc) -> unsigned {
        return mask[cc >> 1] >> ((cc & 1) * 16);
    };

    int bc = 0, bn = 512, bn2 = 1024;     // LDS bufs for chunks c, c+1, c+2
    for (int c = 0; c < full; c++) {
        stage(c + 2, bn2);
        WAITVM(4);                        // forces stage(c) complete; keeps
                                          // stage(c+1), stage(c+2) in flight
        compute(bc, bits_of(c), CH);
        int t = bc; bc = bn; bn = bn2; bn2 = t;
    }
    if (rem) {
        WAITVM(0);
        compute(bc, bits_of(full), rem);
    }

    const size_t o = (((size_t)n * MAXSEG + s) * BATCH + b) * 16;
    segout[o + i2 * 4 + j]       = c_lo;
    segout[o + (i2 + 2) * 4 + j] = c_hi;
}

__global__ __launch_bounds__(256) void amps_combine(
        const float* __restrict__ segout, // (1023, 8, 8, 16)
        const float* __restrict__ diag,   // (1024, 4, 2)
        const float* __restrict__ data,   // (8, 1024)
        float* __restrict__ out)          // (8) — pre-zeroed by memset
{
    const int tid = threadIdx.x;
    const int q   = tid >> 5;             // chain slot in block, 0..7
    const int sub = tid & 31;
    const int b   = sub >> 2;
    const int r   = sub & 3;
    const int n   = blockIdx.x * 8 + q;   // 0..1023 (1023 invalid)

    __shared__ float sh[64];

    float res = 0.0f;
    if (n < NPOS - 1) {
        const int nseg = n / SEGLEN + 1;
        float v = (r == 0) ? 1.0f : 0.0f;
        for (int s2 = 0; s2 < nseg; s2++) {
            const float* p = segout + (((size_t)n * MAXSEG + s2) * BATCH + b) * 16 + r;
            float p0 = p[0], p1 = p[4], p2 = p[8], p3 = p[12];
            float acc = qb<0>(v) * p0;
            acc = fmaf(qb<1>(v), p1, acc);
            acc = fmaf(qb<2>(v), p2, acc);
            v   = fmaf(qb<3>(v), p3, acc);
        }
        const int pos = n + 1;
        const float* dg = diag + pos * 8 + r * 2;
        float o0 = v * dg[0];
        float o1 = v * dg[1];
        o0 += qperm<0xB1>(o0); o0 += qperm<0x4E>(o0);   // quad sum over r
        o1 += qperm<0xB1>(o1); o1 += qperm<0x4E>(o1);
        float mx  = fmaxf(o0, o1);
        float lse = mx + __logf(__expf(o0 - mx) + __expf(o1 - mx));
        float dsel = data[b * NPOS + pos];
        res = ((dsel == 1.0f) ? o0 : o1) - lse;
    }
    if (r == 0) sh[q * 8 + b] = res;
    __syncthreads();
    if (tid < 8) {
        float ssum = 0.0f;
        #pragma unroll
        for (int qq = 0; qq < 8; qq++) ssum += sh[qq * 8 + tid];
        if (blockIdx.x == 0) {
            float o0 = diag[0], o1 = diag[1];
            float mx  = fmaxf(o0, o1);
            float lse = mx + __logf(__expf(o0 - mx) + __expf(o1 - mx));
            float d0  = data[tid * NPOS];
            ssum += ((d0 == 1.0f) ? o0 : o1) - lse;
        }
        atomicAdd(out + tid, ssum);
    }
}

extern "C" void kernel_launch(void* const* d_in, const int* in_sizes, int n_in,
                              void* d_out, int out_size, void* d_ws, size_t ws_size,
                              hipStream_t stream)
{
    const float* data = (const float*)d_in[0];   // (8, 1024)
    const float* tri  = (const float*)d_in[1];   // (523776, 4, 4, 2)
    const float* diag = (const float*)d_in[2];   // (1024, 4, 2)

    float* segout = (float*)d_ws;                // 1023*8*8*16*4 = 4,190,208 B
    float* out    = (float*)d_out;               // 8 floats

    hipMemsetAsync(d_out, 0, 8 * sizeof(float), stream);
    amps_seg<<<dim3(NTASK / 4), dim3(256), 0, stream>>>(data, tri, segout);
    amps_combine<<<dim3(128), dim3(256), 0, stream>>>(segout, diag, data, out);
}

// Round 6
// 118.931 us; speedup vs baseline: 2.1806x; 1.0146x over previous
//
#include <hip/hip_runtime.h>

// AMPS chain kernel v6 — row-per-lane, DPP-free inner loop. gfx950.
//
// amps_seg: each 64-lane wave processes TWO (chain,segment) tasks (32 lanes
// each). Lane = (task t, batch b, row i) holds row i of the running 4x4
// product C in 4 VGPRs. Step update C[i][j] = sum_k C[i][k]*M[k][j] = 16
// register FMAs (4 independent chains of 4) — no DPP, no cross-lane deps.
// M[k][j] read from LDS-staged raw tri (ds_read2, offsets in immediates).
// Staging: CH=8-step (1KB) chunks, one global_load_lds width=16 per task
// per chunk, NBUF=4 buffers, WAITVM(6) = constant distance-3 pipeline.
// Task-length mismatch within a wave: tail LDS slots are overwritten with
// IDENTITY matrices so extra steps are no-ops (uniform compute, no masks).
// Tasks paired adjacent in a length-sorted flat list -> mismatch <=1 step
// except 4 class-boundary waves (negligible waste).
// segout stores P^T so combine reads each segment matrix as one float4.

#define NPOS   1024
#define SEGLEN 128
#define MAXSEG 8
#define CH     8
#define NBUF   4
#define NWAVE  2300                    // 4600 tasks / 2 per wave
#define TRI_ELEMS (523776 * 32)

template<int l>
__device__ __forceinline__ float qb(float x) {
    constexpr int ctrl = l * 0x55;     // quad_perm broadcast lane l
    return __int_as_float(__builtin_amdgcn_update_dpp(
        __float_as_int(x), __float_as_int(x), ctrl, 0xF, 0xF, false));
}
template<int ctrl>
__device__ __forceinline__ float qperm(float x) {
    return __int_as_float(__builtin_amdgcn_update_dpp(
        __float_as_int(x), __float_as_int(x), ctrl, 0xF, 0xF, false));
}

__device__ __forceinline__ void gl_lds16(const float* g, float* l) {
    __builtin_amdgcn_global_load_lds(
        (const __attribute__((address_space(1))) void*)g,
        (__attribute__((address_space(3))) void*)l, 16, 0, 0);
}

// wait until <=N vmem ops outstanding (N<=15); lgkm/exp ignored (gfx9 enc)
#define WAITVM(N) __builtin_amdgcn_s_waitcnt((N) | 0x0F70)

__device__ __forceinline__ void decode_task(int id, int& s, int& n) {
    int base = 0, cnt = 1023;
    s = 0;
    while (id >= base + cnt) { base += cnt; s++; cnt -= 128; }
    n = 1022 - (id - base);            // long chains first within each class
}

__global__ __launch_bounds__(64) void amps_seg(
        const float* __restrict__ data,   // (8, 1024)
        const float* __restrict__ tri,    // (523776, 4, 4, 2)
        float* __restrict__ segout)       // (1023, 8, 8, 4, 4) = P^T per seg
{
    const int lane = threadIdx.x;
    const int w    = blockIdx.x;          // wave id 0..2299
    const int t    = lane >> 5;           // task half 0/1
    const int q    = lane & 31;
    const int b    = q >> 2;              // batch
    const int i    = q & 3;               // row of C (also mask-quarter role)

    int sA, nA, sB, nB;
    decode_task(2 * w,     sA, nA);
    decode_task(2 * w + 1, sB, nB);
    const int g0A = sA * SEGLEN,            g0B = sB * SEGLEN;
    const int stepsA = min(SEGLEN, nA + 1 - g0A);
    const int stepsB = min(SEGLEN, nB + 1 - g0B);
    const int tstA = (nA * (nA + 1) / 2 + g0A) * 32;
    const int tstB = (nB * (nB + 1) / 2 + g0B) * 32;

    const int nchA = (stepsA >> 3) + ((stepsA & 7) ? 1 : 0);
    const int nchB = (stepsB >> 3) + ((stepsB & 7) ? 1 : 0);
    const int nch  = max(nchA, nchB);     // wave-uniform loop bound

    // my-task view (per lane; uniform per half-wave)
    const int g0_my    = t ? g0B : g0A;
    const int steps_my = t ? stepsB : stepsA;
    const int chunkf   = steps_my >> 3;
    const int rem      = steps_my & 7;
    const int n_my     = t ? nB : nA;
    const int s_my     = t ? sB : sA;

    __shared__ float lds[2][NBUF * CH * 32];   // 2 tasks x 1KB x 4 bufs

    // ---- per-lane 128-bit sel mask (bit=1 where data != 1.0) ----
    // half-lane q covers (batch q>>2, quarter q&3): 32 positions.
    unsigned m0, m1, m2, m3;
    {
        const float4* dp4 =
            (const float4*)(data + b * NPOS + g0_my + i * 32);
        float4 f[8];
        #pragma unroll
        for (int u = 0; u < 8; u++) f[u] = dp4[u];
        unsigned piece = 0;
        #pragma unroll
        for (int u = 0; u < 8; u++) {
            piece |= (f[u].x != 1.0f) ? (1u << (u * 4 + 0)) : 0u;
            piece |= (f[u].y != 1.0f) ? (1u << (u * 4 + 1)) : 0u;
            piece |= (f[u].z != 1.0f) ? (1u << (u * 4 + 2)) : 0u;
            piece |= (f[u].w != 1.0f) ? (1u << (u * 4 + 3)) : 0u;
        }
        m0 = (unsigned)__shfl((int)piece, t * 32 + b * 4 + 0);
        m1 = (unsigned)__shfl((int)piece, t * 32 + b * 4 + 1);
        m2 = (unsigned)__shfl((int)piece, t * 32 + b * 4 + 2);
        m3 = (unsigned)__shfl((int)piece, t * 32 + b * 4 + 3);
    }

    auto stageA = [&](int c) {
        int off = min(tstA + c * 256 + lane * 4, TRI_ELEMS - 4);
        gl_lds16(tri + off, &lds[0][(c & (NBUF - 1)) * 256]);
    };
    auto stageB = [&](int c) {
        int off = min(tstB + c * 256 + lane * 4, TRI_ELEMS - 4);
        gl_lds16(tri + off, &lds[1][(c & (NBUF - 1)) * 256]);
    };

    stageA(0); stageB(0);
    stageA(1); stageB(1);
    stageA(2); stageB(2);

    float* __restrict__ mybuf = &lds[t][0];

    float c0 = (i == 0) ? 1.0f : 0.0f;    // row i of identity
    float c1 = (i == 1) ? 1.0f : 0.0f;
    float c2 = (i == 2) ? 1.0f : 0.0f;
    float c3 = (i == 3) ? 1.0f : 0.0f;

    const float idval = ((q >> 3) == ((q >> 1) & 3)) ? 1.0f : 0.0f;

    for (int c = 0; c < nch; c++) {
        stageA(c + 3); stageB(c + 3);
        WAITVM(6);                         // chunk c staged; c+1..c+3 in flight

        // identity-fill tail slots of my task's buffer (rare path)
        if (c >= chunkf) {
            const int mstart = (c == chunkf) ? rem : 0;
            float* bp = mybuf + (c & (NBUF - 1)) * 256 + q;
            for (int m = mstart; m < CH; m++) bp[m * 32] = idval;
        }

        unsigned word = (c < 8) ? ((c < 4) ? m0 : m1) : ((c < 12) ? m2 : m3);
        const unsigned bits = (word >> ((c & 3) * 8)) & 0xFFu;
        const float* __restrict__ buf = mybuf + (c & (NBUF - 1)) * 256;

        #pragma unroll
        for (int m = 0; m < CH; m++) {
            const float* p = buf + m * 32 + ((bits >> m) & 1u);
            // M[k][j] at p[k*8 + j*2]; 4 independent FMA chains (j=0..3)
            float n0 = fmaf(c3, p[24], fmaf(c2, p[16], fmaf(c1, p[8],  c0 * p[0])));
            float n1 = fmaf(c3, p[26], fmaf(c2, p[18], fmaf(c1, p[10], c0 * p[2])));
            float n2 = fmaf(c3, p[28], fmaf(c2, p[20], fmaf(c1, p[12], c0 * p[4])));
            float n3 = fmaf(c3, p[30], fmaf(c2, p[22], fmaf(c1, p[14], c0 * p[6])));
            c0 = n0; c1 = n1; c2 = n2; c3 = n3;
        }
    }

    // store P^T: element [j][i] = P[i][j] = c_j  (combine reads row r as float4)
    const size_t o = (((size_t)n_my * MAXSEG + s_my) * 8 + b) * 16 + i;
    segout[o +  0] = c0;
    segout[o +  4] = c1;
    segout[o +  8] = c2;
    segout[o + 12] = c3;
}

__global__ __launch_bounds__(256) void amps_combine(
        const float* __restrict__ segout, // (1023, 8, 8, 16) P^T
        const float* __restrict__ diag,   // (1024, 4, 2)
        const float* __restrict__ data,   // (8, 1024)
        float* __restrict__ out)          // (8) — pre-zeroed by memset
{
    const int tid = threadIdx.x;
    const int q   = tid >> 5;             // chain slot in block, 0..7
    const int sub = tid & 31;
    const int b   = sub >> 2;
    const int r   = sub & 3;
    const int n   = blockIdx.x * 8 + q;   // 0..1023 (1023 invalid)

    __shared__ float sh[64];

    float res = 0.0f;
    if (n < NPOS - 1) {
        const int nseg = n / SEGLEN + 1;
        // prefetch all 8 segment columns (float4 each; unused slots garbage)
        const float* basep = segout + (size_t)n * (MAXSEG * 128)
                           + b * 16 + r * 4;
        float4 P[8];
        #pragma unroll
        for (int s2 = 0; s2 < 8; s2++)
            P[s2] = *(const float4*)(basep + s2 * 128);

        float v = (r == 0) ? 1.0f : 0.0f;
        #pragma unroll
        for (int s2 = 0; s2 < 8; s2++) {
            float acc = qb<0>(v) * P[s2].x;
            acc = fmaf(qb<1>(v), P[s2].y, acc);
            acc = fmaf(qb<2>(v), P[s2].z, acc);
            float vn = fmaf(qb<3>(v), P[s2].w, acc);
            v = (s2 < nseg) ? vn : v;
        }

        const int pos = n + 1;
        const float* dg = diag + pos * 8 + r * 2;
        float o0 = v * dg[0];
        float o1 = v * dg[1];
        o0 += qperm<0xB1>(o0); o0 += qperm<0x4E>(o0);   // quad sum over r
        o1 += qperm<0xB1>(o1); o1 += qperm<0x4E>(o1);
        float mx  = fmaxf(o0, o1);
        float lse = mx + __logf(__expf(o0 - mx) + __expf(o1 - mx));
        float dsel = data[b * NPOS + pos];
        res = ((dsel == 1.0f) ? o0 : o1) - lse;
    }
    if (r == 0) sh[q * 8 + b] = res;
    __syncthreads();
    if (tid < 8) {
        float ssum = 0.0f;
        #pragma unroll
        for (int qq = 0; qq < 8; qq++) ssum += sh[qq * 8 + tid];
        if (blockIdx.x == 0) {
            float o0 = diag[0], o1 = diag[1];
            float mx  = fmaxf(o0, o1);
            float lse = mx + __logf(__expf(o0 - mx) + __expf(o1 - mx));
            float d0  = data[tid * NPOS];
            ssum += ((d0 == 1.0f) ? o0 : o1) - lse;
        }
        atomicAdd(out + tid, ssum);
    }
}

extern "C" void kernel_launch(void* const* d_in, const int* in_sizes, int n_in,
                              void* d_out, int out_size, void* d_ws, size_t ws_size,
                              hipStream_t stream)
{
    const float* data = (const float*)d_in[0];   // (8, 1024)
    const float* tri  = (const float*)d_in[1];   // (523776, 4, 4, 2)
    const float* diag = (const float*)d_in[2];   // (1024, 4, 2)

    float* segout = (float*)d_ws;                // 1023*8*8*16*4 = 4,190,208 B
    float* out    = (float*)d_out;               // 8 floats

    hipMemsetAsync(d_out, 0, 8 * sizeof(float), stream);
    amps_seg<<<dim3(NWAVE), dim3(64), 0, stream>>>(data, tri, segout);
    amps_combine<<<dim3(128), dim3(256), 0, stream>>>(segout, diag, data, out);
}